// Round 7
// baseline (6699.152 us; speedup 1.0000x reference)
//
#include <hip/hip_runtime.h>

typedef __attribute__((ext_vector_type(8))) short short8;
typedef __attribute__((ext_vector_type(4))) float floatx4;

#define T_STEPS 1024
#define BATCH   256
#define INSZ    128
#define HID     512
#define OUTSZ   32

#define MFMA16(a,b,c) __builtin_amdgcn_mfma_f32_16x16x32_bf16((a),(b),(c),0,0,0)

// bf16 helpers (RNE)
static __device__ __forceinline__ short f2bf(float f) {
  unsigned int u = __float_as_uint(f);
  u += 0x7fffu + ((u >> 16) & 1u);
  return (short)(u >> 16);
}
static __device__ __forceinline__ float bf2f(short s) {
  return __uint_as_float(((unsigned int)(unsigned short)s) << 16);
}
// packed f32->bf16 (RNE), 1 inst for 2 values
static __device__ __forceinline__ unsigned cvt_pk_bf16(float lo, float hi) {
  unsigned r;
  asm("v_cvt_pk_bf16_f32 %0, %1, %2" : "=v"(r) : "v"(lo), "v"(hi));
  return r;
}

// ---------------------------------------------------------------------------
// Pack weights into MFMA B-fragment-linear bf16 layouts.
// B-frag for 16x16x32: lane = ((k%32)/8)*16 + (n%16), elem j = k%8.
// frag id = kt*NT + nt ; pos = (frag*64 + lane)*8 + j
// ---------------------------------------------------------------------------
__global__ __launch_bounds__(256) void pack_kernel(
    const float* __restrict__ W_rec, const float* __restrict__ W_in,
    const float* __restrict__ W_out,
    short* __restrict__ w_rec_p, short* __restrict__ w_in_p,
    short* __restrict__ w_out_p) {
  int i = blockIdx.x * 256 + threadIdx.x;  // 0..262143
  {
    // W_rec[n][k] used as B[k][n]  (h @ W_rec^T)
    int n = i >> 9, k = i & 511;
    int pos = ((((k >> 5) * 32 + (n >> 4)) * 64 + ((k >> 3) & 3) * 16 + (n & 15)) << 3) + (k & 7);
    w_rec_p[pos] = f2bf(W_rec[i]);
  }
  if (i < INSZ * HID) {
    int k = i >> 9, n = i & 511;  // W_in[k][n] used as B[k][n]
    int pos = ((((k >> 5) * 32 + (n >> 4)) * 64 + ((k >> 3) & 3) * 16 + (n & 15)) << 3) + (k & 7);
    w_in_p[pos] = f2bf(W_in[i]);
  }
  if (i < HID * OUTSZ) {
    int k = i >> 5, o = i & 31;   // W_out[k][o] used as B[k][o], NT=2
    int pos = ((((k >> 5) * 2 + (o >> 4)) * 64 + ((k >> 3) & 3) * 16 + (o & 15)) << 3) + (k & 7);
    w_out_p[pos] = f2bf(W_out[i]);
  }
}

// ---------------------------------------------------------------------------
// Fused kernel (512 thr = 8 waves), one launch per chunk phase c:
//   blocks [0,32)         : scan of chunk c. Block s: rows (s>>1)*16..+16,
//                           columns (s&1)*256..+256.
//   blocks [32, 32+chunk) : xproj of chunk c+1 (one timestep per block)
//   remaining chunk blocks: out GEMM of chunk c-1
//
// Scan step structure (overlapped exchange — r6's handshake was ~3600 cy of
// serial tail per step):
//   P1 publish own h_t (A-frag-ready row-major) to xch[g&1][s] + hs store
//   P3 vmcnt(0); barrier; tid0: flag[s]=g (release)          <- post EARLY
//   P2 own-k-half MFMAs (afr from LDS hbuf; this block computed those h cols)
//   P4 per-wave acquire-poll flag[ps]>=g; partner afr DIRECT from xch (L2),
//      no LDS staging, no extra barrier; partner-k MFMAs
//   P5 epilogue -> hbuf[p^1] own half; barrier
// Flag propagation latency hides under P2; 2 barriers/step; hbuf is own-half
// only (2 x 8KB). t=0 of a chunk reads partner half from bf16 carry (hbc)
// written at the previous chunk's tail — post-then-wait => deadlock-free;
// parity-slot reuse safe by the one-step-lag argument (overwrite of h_{g-2}
// slot at step g is ordered after partner's step g-1 flag, which follows its
// consumption of h_{g-2}). Poll has an escape cap: bug => wrong data, not hang.
// W residency as r6: regs kt0..7 (64 VGPR), LDS kt8..15 (128KB), own columns.
// ---------------------------------------------------------------------------
__global__ __launch_bounds__(512, 1) void fused_kernel(
    const float* __restrict__ inputs,
    const short* __restrict__ w_rec_p, const short* __restrict__ w_in_p,
    const short* __restrict__ w_out_p,
    const float* __restrict__ b_rec, const float* __restrict__ b_out,
    short* __restrict__ xp0, short* __restrict__ xp1,
    short* __restrict__ hs0, short* __restrict__ hs1,
    float* __restrict__ h_carry, short* __restrict__ hbc,
    float* __restrict__ out,
    short* __restrict__ xch, unsigned* __restrict__ flags,
    int c, int chunk, int nchunks) {
  __shared__ __align__(16) char smem[163840];  // scan 144K / out 8*16640
  const int tid  = threadIdx.x;
  const int wave = tid >> 6, lane = tid & 63;
  const int l15  = lane & 15, q = lane >> 4;

  const int sb = (c >= 0 && c < nchunks) ? 32 : 0;
  const int nx = (c + 1 < nchunks) ? chunk : 0;
  const int bid = blockIdx.x;

  if (bid < sb) {
    // ================= scan role ===========================================
    short* w_lds = (short*)smem;               // 128 KB: kt 8..15, own cols
    short* hbuf  = (short*)(smem + 131072);    // 2 x 8KB own-half h (swizzled)
    const short* xp = (c & 1) ? xp1 : xp0;
    short* hs = (c & 1) ? hs1 : hs0;
    const int s    = bid;
    const int slab = s >> 1;                   // batch slab index
    const int ch   = s & 1;                    // column half
    const int ps   = s ^ 1;                    // partner block
    const int pch  = ch ^ 1;
    const int first = (c == 0);

    // registers: kt 0..7, own 2 col tiles per wave (64 VGPR)
    short8 wreg[8][2];
    #pragma unroll
    for (int kt = 0; kt < 8; ++kt)
      #pragma unroll
      for (int i = 0; i < 2; ++i) {
        int ct = (ch << 4) + wave * 2 + i;
        wreg[kt][i] = *(const short8*)(w_rec_p + (((kt * 32 + ct) * 64 + lane) << 3));
      }

    // LDS: kt 8..15, all 16 col tiles of own half (8192 shorts per kt)
    for (int e = tid * 8; e < 8 * 16 * 512; e += 512 * 8) {
      int kt8 = e >> 13;
      int rest = e & 8191;
      *(short8*)(w_lds + e) =
          *(const short8*)(w_rec_p + ((8 + kt8) * 32 + (ch << 4)) * 512 + rest);
    }

    // hbuf[0]: own half of h, swizzled [16 rows][32 chunks of 8 cols]
    float hold[2][4];
    #pragma unroll
    for (int i = 0; i < 2; ++i) {
      int colLocal = wave * 32 + i * 16 + l15;
      int cc = colLocal >> 3, cl = colLocal & 7;
      #pragma unroll
      for (int r = 0; r < 4; ++r) {
        int row = q * 4 + r;
        float v = first ? 0.f
                        : h_carry[(size_t)(slab * 16 + row) * HID + (ch << 8) + colLocal];
        hold[i][r] = v;
        hbuf[row * 256 + ((cc ^ row) << 3) + cl] = f2bf(v);
      }
    }

    const float alpha = (float)(0.1 / 100.0);
    const float onem  = (float)(1.0 - 0.1 / 100.0);

    __syncthreads();

    int p = 0;
    for (int t = 0; t < chunk; ++t) {
      const int g = c * chunk + t;                  // global state index
      short* hb  = hbuf + p * 4096;                 // own half of h_g
      short* hnb = hbuf + (p ^ 1) * 4096;

      if (t > 0) {
        // P1: publish own h_g + hs[t-1] (one LDS read feeds both stores)
        int row = tid >> 5, cc = tid & 31;
        short8 v = *(const short8*)(hb + row * 256 + ((cc ^ row) << 3));
        short* slot = xch + (((size_t)(g & 1) * 32 + s) << 12);
        *(short8*)(slot + row * 256 + cc * 8) = v;
        *(short8*)(hs + ((size_t)(t - 1) * BATCH + slab * 16 + row) * HID + (ch << 8) + cc * 8) = v;
        // P3: drain stores; all-waves barrier; post flag (release)
        asm volatile("s_waitcnt vmcnt(0)" ::: "memory");
        __syncthreads();
        if (tid == 0)
          __hip_atomic_store(&flags[s], (unsigned)g,
                             __ATOMIC_RELEASE, __HIP_MEMORY_SCOPE_AGENT);
      }

      // xp[t] own tiles (consumed in epilogue; latency under MFMAs)
      uint2 xq[2];
      #pragma unroll
      for (int i = 0; i < 2; ++i)
        xq[i] = *(const uint2*)(xp + ((((size_t)t * 16 + slab) * 32 + (ch << 4) + wave * 2 + i) * 64 + lane) * 4);

      floatx4 acc[2];
      acc[0] = (floatx4){0.f, 0.f, 0.f, 0.f};
      acc[1] = (floatx4){0.f, 0.f, 0.f, 0.f};

      // P2: own-k-half MFMAs (afr = own h columns, in hbuf)
      #pragma unroll
      for (int ktrel = 0; ktrel < 8; ++ktrel) {
        short8 afr = *(const short8*)(hb + l15 * 256 + (((ktrel * 4 + q) ^ l15) << 3));
        if (ch == 0) {   // own k-tiles = kt 0..7 = register weights
          acc[0] = MFMA16(afr, wreg[ktrel][0], acc[0]);
          acc[1] = MFMA16(afr, wreg[ktrel][1], acc[1]);
        } else {         // own k-tiles = kt 8..15 = LDS weights
          short8 b0 = *(const short8*)(w_lds + ktrel * 8192 + (wave * 2 + 0) * 512 + lane * 8);
          short8 b1 = *(const short8*)(w_lds + ktrel * 8192 + (wave * 2 + 1) * 512 + lane * 8);
          acc[0] = MFMA16(afr, b0, acc[0]);
          acc[1] = MFMA16(afr, b1, acc[1]);
        }
      }

      // P4: partner-k-half. afr direct from xch (L2) after per-wave poll.
      const short* psrc;
      if (t == 0) {
        psrc = hbc + (size_t)(slab * 16) * HID + (pch << 8);   // stride HID
      } else {
        unsigned iters = 0;
        while (__hip_atomic_load(&flags[ps], __ATOMIC_ACQUIRE,
                                 __HIP_MEMORY_SCOPE_AGENT) < (unsigned)g) {
          __builtin_amdgcn_s_sleep(2);
          if (++iters > (1u << 20)) break;                     // no-hang escape
        }
        psrc = xch + (((size_t)(g & 1) * 32 + ps) << 12);      // stride 256
      }
      const int pstride = (t == 0) ? HID : 256;
      #pragma unroll
      for (int ktrel = 0; ktrel < 8; ++ktrel) {
        short8 afr = *(const short8*)(psrc + l15 * pstride + ktrel * 32 + q * 8);
        if (ch == 0) {   // partner k-tiles = kt 8..15 = LDS weights
          short8 b0 = *(const short8*)(w_lds + ktrel * 8192 + (wave * 2 + 0) * 512 + lane * 8);
          short8 b1 = *(const short8*)(w_lds + ktrel * 8192 + (wave * 2 + 1) * 512 + lane * 8);
          acc[0] = MFMA16(afr, b0, acc[0]);
          acc[1] = MFMA16(afr, b1, acc[1]);
        } else {         // partner k-tiles = kt 0..7 = register weights
          acc[0] = MFMA16(afr, wreg[ktrel][0], acc[0]);
          acc[1] = MFMA16(afr, wreg[ktrel][1], acc[1]);
        }
      }

      // P5: epilogue — CTRNN update fp32; own h_{g+1} -> other hbuf
      #pragma unroll
      for (int i = 0; i < 2; ++i) {
        int colLocal = wave * 32 + i * 16 + l15;
        int cc = colLocal >> 3, cl = colLocal & 7;
        float x0 = bf2f((short)(xq[i].x & 0xffffu));
        float x1 = bf2f((short)(xq[i].x >> 16));
        float x2 = bf2f((short)(xq[i].y & 0xffffu));
        float x3 = bf2f((short)(xq[i].y >> 16));
        float h0 = onem * hold[i][0] + alpha * fmaxf(acc[i][0] + x0, 0.f);
        float h1 = onem * hold[i][1] + alpha * fmaxf(acc[i][1] + x1, 0.f);
        float h2 = onem * hold[i][2] + alpha * fmaxf(acc[i][2] + x2, 0.f);
        float h3 = onem * hold[i][3] + alpha * fmaxf(acc[i][3] + x3, 0.f);
        hold[i][0] = h0; hold[i][1] = h1; hold[i][2] = h2; hold[i][3] = h3;
        unsigned u01 = cvt_pk_bf16(h0, h1);
        unsigned u23 = cvt_pk_bf16(h2, h3);
        int r0 = q * 4;
        hnb[(r0 + 0) * 256 + ((cc ^ (r0 + 0)) << 3) + cl] = (short)(u01 & 0xffffu);
        hnb[(r0 + 1) * 256 + ((cc ^ (r0 + 1)) << 3) + cl] = (short)(u01 >> 16);
        hnb[(r0 + 2) * 256 + ((cc ^ (r0 + 2)) << 3) + cl] = (short)(u23 & 0xffffu);
        hnb[(r0 + 3) * 256 + ((cc ^ (r0 + 3)) << 3) + cl] = (short)(u23 >> 16);
      }
      __syncthreads();   // hnb complete; also orders next-step P1 reads
      p ^= 1;
    }

    // tail: hs[chunk-1] + bf16 carry (hbc) + fp32 carry (own half each)
    {
      const short* hb = hbuf + p * 4096;
      int row = tid >> 5, cc = tid & 31;
      short8 v = *(const short8*)(hb + row * 256 + ((cc ^ row) << 3));
      *(short8*)(hs + ((size_t)(chunk - 1) * BATCH + slab * 16 + row) * HID + (ch << 8) + cc * 8) = v;
      *(short8*)(hbc + (size_t)(slab * 16 + row) * HID + (ch << 8) + cc * 8) = v;
    }
    #pragma unroll
    for (int i = 0; i < 2; ++i) {
      int colLocal = wave * 32 + i * 16 + l15;
      #pragma unroll
      for (int r = 0; r < 4; ++r)
        h_carry[(size_t)(slab * 16 + q * 4 + r) * HID + (ch << 8) + colLocal] = hold[i][r];
    }

  } else if (bid - sb < nx) {
    // ================= xproj role: one timestep of chunk c+1 ================
    const int tt = bid - sb;
    const int cc = c + 1;
    short* xpw = (cc & 1) ? xp1 : xp0;
    const int t_abs = cc * chunk + tt;

    short8 bfr[4][4];  // ct = wave*4+i, kt 0..3
    #pragma unroll
    for (int i = 0; i < 4; ++i)
      #pragma unroll
      for (int kt = 0; kt < 4; ++kt)
        bfr[i][kt] = *(const short8*)(w_in_p + (((kt * 32 + wave * 4 + i) * 64 + lane) << 3));
    float brv[4];
    #pragma unroll
    for (int i = 0; i < 4; ++i) brv[i] = b_rec[(wave * 4 + i) * 16 + l15];

    for (int it = 0; it < 16; ++it) {
      const float* arow = inputs + ((size_t)t_abs * BATCH + it * 16 + l15) * INSZ + q * 8;
      short8 afr[4];
      #pragma unroll
      for (int kt = 0; kt < 4; ++kt) {
        short8 sv;
        #pragma unroll
        for (int j = 0; j < 4; ++j) {
          unsigned u = cvt_pk_bf16(arow[kt * 32 + 2 * j], arow[kt * 32 + 2 * j + 1]);
          sv[2 * j] = (short)(u & 0xffffu);
          sv[2 * j + 1] = (short)(u >> 16);
        }
        afr[kt] = sv;
      }
      floatx4 acc[4];
      #pragma unroll
      for (int i = 0; i < 4; ++i) acc[i] = (floatx4){0.f, 0.f, 0.f, 0.f};
      #pragma unroll
      for (int kt = 0; kt < 4; ++kt)
        #pragma unroll
        for (int i = 0; i < 4; ++i)
          acc[i] = MFMA16(afr[kt], bfr[i][kt], acc[i]);
      #pragma unroll
      for (int i = 0; i < 4; ++i) {
        unsigned u01 = cvt_pk_bf16(acc[i][0] + brv[i], acc[i][1] + brv[i]);
        unsigned u23 = cvt_pk_bf16(acc[i][2] + brv[i], acc[i][3] + brv[i]);
        uint2 u; u.x = u01; u.y = u23;
        *(uint2*)(xpw + ((((size_t)tt * 16 + it) * 32 + wave * 4 + i) * 64 + lane) * 4) = u;
      }
    }

  } else {
    // ================= out role: one timestep of chunk c-1 ==================
    const int tt = bid - sb - nx;
    const int cc = c - 1;
    const short* hsr = (cc & 1) ? hs1 : hs0;
    short* al = (short*)smem + wave * (16 * 520);  // wave-private padded tile

    float bov[2] = { b_out[l15], b_out[16 + l15] };

    #pragma unroll
    for (int itm = 0; itm < 2; ++itm) {
      int mt = wave * 2 + itm;
      const short* src = hsr + ((size_t)tt * BATCH + mt * 16) * HID;
      #pragma unroll
      for (int r = 0; r < 16; ++r)
        *(short8*)(al + r * 520 + lane * 8) = *(const short8*)(src + r * 512 + lane * 8);
      // wave-private tile: in-wave DS ordering suffices, no barrier

      floatx4 acc2[2];
      acc2[0] = (floatx4){0.f, 0.f, 0.f, 0.f};
      acc2[1] = (floatx4){0.f, 0.f, 0.f, 0.f};
      #pragma unroll
      for (int kt = 0; kt < 16; ++kt) {
        short8 afr = *(const short8*)(al + l15 * 520 + kt * 32 + q * 8);
        short8 b0 = *(const short8*)(w_out_p + (((kt * 2 + 0) * 64 + lane) << 3));
        short8 b1 = *(const short8*)(w_out_p + (((kt * 2 + 1) * 64 + lane) << 3));
        acc2[0] = MFMA16(afr, b0, acc2[0]);
        acc2[1] = MFMA16(afr, b1, acc2[1]);
      }
      float* outp = out + ((size_t)(cc * chunk + tt) * BATCH + mt * 16) * OUTSZ;
      #pragma unroll
      for (int ot = 0; ot < 2; ++ot)
        #pragma unroll
        for (int r = 0; r < 4; ++r)
          outp[(size_t)(q * 4 + r) * OUTSZ + ot * 16 + l15] = acc2[ot][r] + bov[ot];
    }
  }
}

// ---------------------------------------------------------------------------
extern "C" void kernel_launch(void* const* d_in, const int* in_sizes, int n_in,
                              void* d_out, int out_size, void* d_ws, size_t ws_size,
                              hipStream_t stream) {
  const float* inputs = (const float*)d_in[0];  // [1024,256,128]
  const float* W_rec  = (const float*)d_in[1];  // [512,512]
  const float* W_in   = (const float*)d_in[2];  // [128,512]
  const float* b_rec  = (const float*)d_in[3];  // [512]
  const float* W_out  = (const float*)d_in[4];  // [512,32]
  const float* b_out  = (const float*)d_in[5];  // [32]
  float* out = (float*)d_out;                   // [1024,256,32]

  char* ws = (char*)d_ws;
  // fixed region (< 2 MB) — non-overlapping (r6 had xch/h_carry overlap!)
  short* w_rec_p = (short*)(ws);                        // 512 KB @ 0
  short* w_in_p  = (short*)(ws + 524288);               // 128 KB
  short* w_out_p = (short*)(ws + 655360);               //  32 KB
  float* h_carry = (float*)(ws + 688128);               // 512 KB -> 1212416
  short* xch     = (short*)(ws + 1212416);              // 512 KB -> 1736704
  short* hbc     = (short*)(ws + 1736704);              // 256 KB -> 1998848
  unsigned* flags = (unsigned*)(ws + 1998848);          // 128 B
  const size_t fixed_end = 2u << 20;                    // 2 MB

  // double-buffered xp + hs: 4 buffers of chunk*256KB each
  const size_t per_step = (size_t)BATCH * HID * 2 * 4;
  int chunk = T_STEPS;
  while (chunk > 1 && fixed_end + (size_t)chunk * per_step > ws_size) chunk >>= 1;
  if (fixed_end + (size_t)chunk * per_step > ws_size) return;  // ws too small
  const int nchunks = T_STEPS / chunk;

  const size_t buf = (size_t)chunk * BATCH * HID * 2;  // bytes per buffer
  short* xp0 = (short*)(ws + fixed_end);
  short* xp1 = (short*)(ws + fixed_end + buf);
  short* hs0 = (short*)(ws + fixed_end + 2 * buf);
  short* hs1 = (short*)(ws + fixed_end + 3 * buf);

  hipMemsetAsync(flags, 0, 128, stream);
  hipMemsetAsync(hbc, 0, (size_t)BATCH * HID * 2, stream);  // h_0 = 0
  pack_kernel<<<1024, 256, 0, stream>>>(W_rec, W_in, W_out, w_rec_p, w_in_p, w_out_p);

  for (int c = -1; c <= nchunks; ++c) {
    int sb = (c >= 0 && c < nchunks) ? 32 : 0;
    int nx = (c + 1 >= 0 && c + 1 < nchunks) ? chunk : 0;
    int no = (c - 1 >= 0 && c - 1 < nchunks) ? chunk : 0;
    int grid = sb + nx + no;
    if (!grid) continue;
    fused_kernel<<<grid, 512, 0, stream>>>(inputs, w_rec_p, w_in_p, w_out_p,
        b_rec, b_out, xp0, xp1, hs0, hs1, h_carry, hbc, out, xch, flags,
        c, chunk, nchunks);
  }
}